// Round 1
// baseline (568.887 us; speedup 1.0000x reference)
//
#include <hip/hip_runtime.h>
#include <cmath>

#define B_N 65536
#define C_N 128
#define D_N 32
#define K_N 10
#define CTILE 32
#define EPS_F 1e-12f

// ---------------------------------------------------------------------------
// Prep 1: Sm[c][d] = sum_e S_inv[c][d][e] * mu[c][e]   (C*D = 4096 threads)
// ---------------------------------------------------------------------------
__global__ __launch_bounds__(256) void k_prep_sm(const float* __restrict__ S,
                                                 const float* __restrict__ mu,
                                                 float* __restrict__ Sm) {
    int t = blockIdx.x * 256 + threadIdx.x;     // 0..4095
    int c = t >> 5;
    int d = t & 31;
    const float* Sr = S + (size_t)c * (D_N * D_N) + (size_t)d * D_N;
    const float* mr = mu + (size_t)c * D_N;
    float a0 = 0.f, a1 = 0.f, a2 = 0.f, a3 = 0.f;
#pragma unroll
    for (int e = 0; e < D_N; e += 4) {
        a0 = fmaf(Sr[e + 0], mr[e + 0], a0);
        a1 = fmaf(Sr[e + 1], mr[e + 1], a1);
        a2 = fmaf(Sr[e + 2], mr[e + 2], a2);
        a3 = fmaf(Sr[e + 3], mr[e + 3], a3);
    }
    Sm[t] = (a0 + a1) + (a2 + a3);
}

// ---------------------------------------------------------------------------
// Prep 2: t3[c] = mu[c] . Sm[c];  cls[c] = argmax_k onehot[c][k]
// ---------------------------------------------------------------------------
__global__ __launch_bounds__(128) void k_prep_t3(const float* __restrict__ mu,
                                                 const float* __restrict__ Sm,
                                                 const int* __restrict__ onehot,
                                                 float* __restrict__ t3,
                                                 int* __restrict__ cls) {
    int c = threadIdx.x;           // 128 threads, 1 block
    const float* mr = mu + (size_t)c * D_N;
    const float* sr = Sm + (size_t)c * D_N;
    float a = 0.f;
#pragma unroll
    for (int d = 0; d < D_N; ++d) a = fmaf(mr[d], sr[d], a);
    t3[c] = a;
    int cl = 0;
#pragma unroll
    for (int k = 0; k < K_N; ++k)
        if (onehot[c * K_N + k] != 0) cl = k;
    cls[c] = cl;
}

// ---------------------------------------------------------------------------
// Main: Gamma[c][b] = exp(-0.5 * (z^T Sinv_c z - 2 z.Sm_c + t3_c))
// grid (B/256, C/CTILE), 1 thread = 1 row. S reads are wave-uniform -> SGPR.
// ---------------------------------------------------------------------------
__global__ __launch_bounds__(256) void k_main(const float* __restrict__ data,
                                              const float* __restrict__ S,
                                              const float* __restrict__ Sm,
                                              const float* __restrict__ t3,
                                              float* __restrict__ gws) {
    int b = blockIdx.x * 256 + threadIdx.x;
    int c0 = blockIdx.y * CTILE;

    float z[D_N];
    const float4* dz = (const float4*)(data + (size_t)b * D_N);
#pragma unroll
    for (int i = 0; i < D_N / 4; ++i) {
        float4 v = dz[i];
        z[4 * i + 0] = v.x;
        z[4 * i + 1] = v.y;
        z[4 * i + 2] = v.z;
        z[4 * i + 3] = v.w;
    }

    for (int cc = 0; cc < CTILE; ++cc) {
        int c = c0 + cc;
        const float* Sc = S + (size_t)c * (D_N * D_N);
        float q0 = 0.f, q1 = 0.f, q2 = 0.f, q3 = 0.f;
#pragma unroll
        for (int d = 0; d < D_N; ++d) {
            const float* Sr = Sc + d * D_N;
            float w0 = 0.f, w1 = 0.f, w2 = 0.f, w3 = 0.f;
#pragma unroll
            for (int e = 0; e < D_N; e += 4) {
                w0 = fmaf(Sr[e + 0], z[e + 0], w0);
                w1 = fmaf(Sr[e + 1], z[e + 1], w1);
                w2 = fmaf(Sr[e + 2], z[e + 2], w2);
                w3 = fmaf(Sr[e + 3], z[e + 3], w3);
            }
            float zd = z[d];
            q0 = fmaf(zd, w0, q0);
            q1 = fmaf(zd, w1, q1);
            q2 = fmaf(zd, w2, q2);
            q3 = fmaf(zd, w3, q3);
        }
        // t2 = z . Sm_c
        const float* Smr = Sm + (size_t)c * D_N;
        float s0 = 0.f, s1 = 0.f, s2 = 0.f, s3 = 0.f;
#pragma unroll
        for (int e = 0; e < D_N; e += 4) {
            s0 = fmaf(Smr[e + 0], z[e + 0], s0);
            s1 = fmaf(Smr[e + 1], z[e + 1], s1);
            s2 = fmaf(Smr[e + 2], z[e + 2], s2);
            s3 = fmaf(Smr[e + 3], z[e + 3], s3);
        }
        float t1v = (q0 + q1) + (q2 + q3);
        float t2v = (s0 + s1) + (s2 + s3);
        float d2 = t1v - 2.0f * t2v + t3[c];
        gws[(size_t)c * B_N + b] = expf(-0.5f * d2);   // coalesced store
    }
}

// ---------------------------------------------------------------------------
// Finalize: per row -> sum, cluster argmax, per-class sums, divide, outputs.
// d_out layout (all float32): [B*K label_scores][B preds][B clusters]
// ---------------------------------------------------------------------------
__global__ __launch_bounds__(256) void k_final(const float* __restrict__ gws,
                                               const int* __restrict__ cls,
                                               float* __restrict__ out) {
    int b = blockIdx.x * 256 + threadIdx.x;
    float acc[K_N];
#pragma unroll
    for (int k = 0; k < K_N; ++k) acc[k] = 0.f;
    float sum = 0.f;
    float gmax = -1.f;
    int amax = 0;
    for (int c = 0; c < C_N; ++c) {
        float g = gws[(size_t)c * B_N + b];   // coalesced load
        sum += g;
        if (g > gmax) { gmax = g; amax = c; }
        int cl = cls[c];                      // uniform scalar load
#pragma unroll
        for (int k = 0; k < K_N; ++k) acc[k] += (cl == k) ? g : 0.f;
    }
    float den = sum + EPS_F;
    float ls[K_N];
#pragma unroll
    for (int k = 0; k < K_N; ++k) ls[k] = acc[k] / den;
    float best = -1.f;
    int bk = 0;
#pragma unroll
    for (int k = 0; k < K_N; ++k) {
        if (ls[k] > best) { best = ls[k]; bk = k; }
    }
#pragma unroll
    for (int k = 0; k < K_N; ++k) out[(size_t)b * K_N + k] = ls[k];
    out[(size_t)B_N * K_N + b] = (float)bk;
    out[(size_t)B_N * K_N + B_N + b] = (float)amax;
}

// ---------------------------------------------------------------------------
extern "C" void kernel_launch(void* const* d_in, const int* in_sizes, int n_in,
                              void* d_out, int out_size, void* d_ws, size_t ws_size,
                              hipStream_t stream) {
    const float* data   = (const float*)d_in[0];   // [B, D]
    const float* mu     = (const float*)d_in[1];   // [C, D]
    const float* S      = (const float*)d_in[2];   // [C, D, D]
    const int*   onehot = (const int*)d_in[3];     // [C, K]
    float* out = (float*)d_out;

    // workspace: Gamma [C][B] (32 MB) | Sm [C*D] | t3 [C] | cls [C]
    float* gws = (float*)d_ws;
    float* Sm  = gws + (size_t)C_N * B_N;
    float* t3  = Sm + C_N * D_N;
    int*   cls = (int*)(t3 + C_N);

    hipLaunchKernelGGL(k_prep_sm, dim3((C_N * D_N) / 256), dim3(256), 0, stream,
                       S, mu, Sm);
    hipLaunchKernelGGL(k_prep_t3, dim3(1), dim3(128), 0, stream,
                       mu, Sm, onehot, t3, cls);
    hipLaunchKernelGGL(k_main, dim3(B_N / 256, C_N / CTILE), dim3(256), 0, stream,
                       data, S, Sm, t3, gws);
    hipLaunchKernelGGL(k_final, dim3(B_N / 256), dim3(256), 0, stream,
                       gws, cls, out);
}

// Round 2
// 266.534 us; speedup vs baseline: 2.1344x; 2.1344x over previous
//
#include <hip/hip_runtime.h>
#include <cmath>

#define B_N 65536
#define C_N 128
#define D_N 32
#define DH  33                 // homogeneous dim (z, 1)
#define TRI 561                // 33*34/2 packed upper triangle
#define PPAD 576               // padded row (16B-aligned, whole dwordx16s)
#define K_N 10
#define CTILE 16
#define EPS_F 1e-12f
#define SCALE_F (-0.72134752044448169f)   // -0.5 * log2(e)

// ---------------------------------------------------------------------------
// Prep 1: Sm[c][d] = sum_e S_inv[c][d][e] * mu[c][e]
// ---------------------------------------------------------------------------
__global__ __launch_bounds__(256) void k_prep_sm(const float* __restrict__ S,
                                                 const float* __restrict__ mu,
                                                 float* __restrict__ Sm) {
    int t = blockIdx.x * 256 + threadIdx.x;     // 0..4095
    int c = t >> 5;
    int d = t & 31;
    const float* Sr = S + (size_t)c * (D_N * D_N) + (size_t)d * D_N;
    const float* mr = mu + (size_t)c * D_N;
    float a0 = 0.f, a1 = 0.f, a2 = 0.f, a3 = 0.f;
#pragma unroll
    for (int e = 0; e < D_N; e += 4) {
        a0 = fmaf(Sr[e + 0], mr[e + 0], a0);
        a1 = fmaf(Sr[e + 1], mr[e + 1], a1);
        a2 = fmaf(Sr[e + 2], mr[e + 2], a2);
        a3 = fmaf(Sr[e + 3], mr[e + 3], a3);
    }
    Sm[t] = (a0 + a1) + (a2 + a3);
}

// ---------------------------------------------------------------------------
// Prep 2: t3[c] = mu[c].Sm[c];  cls[c] = argmax_k onehot[c][k]
// ---------------------------------------------------------------------------
__global__ __launch_bounds__(128) void k_prep_misc(const float* __restrict__ mu,
                                                   const float* __restrict__ Sm,
                                                   const int* __restrict__ onehot,
                                                   float* __restrict__ t3,
                                                   int* __restrict__ cls) {
    int c = threadIdx.x;
    const float* mr = mu + (size_t)c * D_N;
    const float* sr = Sm + (size_t)c * D_N;
    float a = 0.f;
#pragma unroll
    for (int d = 0; d < D_N; ++d) a = fmaf(mr[d], sr[d], a);
    t3[c] = a;
    int cl = 0;
#pragma unroll
    for (int k = 0; k < K_N; ++k)
        if (onehot[c * K_N + k] != 0) cl = k;
    cls[c] = cl;
}

// ---------------------------------------------------------------------------
// Prep 3: pack P[c][t] = SCALE * Mhat[c] upper triangle, homogeneous 33x33.
//   Mhat[d][e] (d<=e):  d,e<32: S[d][e] * (d==e ? 1 : 2)
//                       e==32, d<32:  -2*Sm[d]
//                       d==e==32:     t3
// So that  -0.5*log2e*d2[b,c] = sum_{d<=e} P * y_d * y_e, y=[z,1].
// ---------------------------------------------------------------------------
__global__ __launch_bounds__(256) void k_pack(const float* __restrict__ S,
                                              const float* __restrict__ Sm,
                                              const float* __restrict__ t3,
                                              float* __restrict__ P) {
    int c = blockIdx.x;
#pragma unroll
    for (int it = 0; it < 3; ++it) {
        int t = it * 256 + threadIdx.x;
        if (t >= TRI) continue;
        int d = 0;
        while ((d + 1) * (66 - d) / 2 <= t) ++d;        // row start off(d)=d*(67-d)/2
        int e = d + (t - d * (67 - d) / 2);
        float v;
        if (e < D_N) {
            v = S[(size_t)c * (D_N * D_N) + d * D_N + e] * (d == e ? 1.f : 2.f);
        } else if (d < D_N) {
            v = -2.f * Sm[c * D_N + d];
        } else {
            v = t3[c];
        }
        P[(size_t)c * PPAD + t] = SCALE_F * v;
    }
}

// ---------------------------------------------------------------------------
// Main: Gamma[c][b] = exp2( sum_{d<=e} P[c] y_d y_e )   (scale pre-folded)
// grid (B/256, C/CTILE). P reads are wave-uniform -> scalar loads.
// ---------------------------------------------------------------------------
__global__ __launch_bounds__(256) void k_main(const float* __restrict__ data,
                                              const float* __restrict__ P,
                                              float* __restrict__ gws) {
    int b = blockIdx.x * 256 + threadIdx.x;
    int c0 = blockIdx.y * CTILE;

    float y[DH];
    const float4* dz = (const float4*)(data + (size_t)b * D_N);
#pragma unroll
    for (int i = 0; i < D_N / 4; ++i) {
        float4 v = dz[i];
        y[4 * i + 0] = v.x;
        y[4 * i + 1] = v.y;
        y[4 * i + 2] = v.z;
        y[4 * i + 3] = v.w;
    }
    y[32] = 1.0f;

    for (int cc = 0; cc < CTILE; ++cc) {
        const float* Pc = P + (size_t)(c0 + cc) * PPAD;
        float a0 = 0.f, a1 = 0.f;
        int idx = 0;
#pragma unroll
        for (int d = 0; d < DH; ++d) {
            float u0 = 0.f, u1 = 0.f;
            const int n = DH - d;
#pragma unroll
            for (int j = 0; j < n; ++j) {
                float p = Pc[idx + j];
                if (j & 1) u1 = fmaf(p, y[d + j], u1);
                else       u0 = fmaf(p, y[d + j], u0);
            }
            idx += n;
            float ud = u0 + u1;
            if (d & 1) a1 = fmaf(y[d], ud, a1);
            else       a0 = fmaf(y[d], ud, a0);
        }
        float acc = a0 + a1;            // = -0.5*log2e * d2  (<= ~0)
        float g;
        asm("v_exp_f32 %0, %1" : "=v"(g) : "v"(acc));   // 2^acc = exp(-0.5 d2)
        gws[(size_t)(c0 + cc) * B_N + b] = g;            // coalesced store
    }
}

// ---------------------------------------------------------------------------
// Finalize: 4 waves per 64 rows; each wave scans a 32-cluster chunk, LDS
// combine. d_out (float32): [B*K scores][B preds][B clusters]
// ---------------------------------------------------------------------------
__global__ __launch_bounds__(256) void k_final(const float* __restrict__ gws,
                                               const int* __restrict__ cls,
                                               float* __restrict__ out) {
    __shared__ float comb[4][64][16];   // [chunk][row][sum,gmax,amax,acc0..9]
    int tid   = threadIdx.x;
    int lane  = tid & 63;               // row within block
    int chunk = tid >> 6;               // wave id = c-chunk
    int b0 = blockIdx.x * 64;
    int b  = b0 + lane;

    float s = 0.f, gmax = -1.f;
    int amax = 0;
    float a0 = 0, a1 = 0, a2 = 0, a3 = 0, a4 = 0, a5 = 0, a6 = 0, a7 = 0, a8 = 0, a9 = 0;
    int cbase = chunk * 32;
    for (int i = 0; i < 32; ++i) {
        int c = cbase + i;
        float g = gws[(size_t)c * B_N + b];     // 256B coalesced per wave
        s += g;
        if (g > gmax) { gmax = g; amax = c; }
        int cl = cls[c];                        // wave-uniform scalar
        if      (cl == 0) a0 += g;
        else if (cl == 1) a1 += g;
        else if (cl == 2) a2 += g;
        else if (cl == 3) a3 += g;
        else if (cl == 4) a4 += g;
        else if (cl == 5) a5 += g;
        else if (cl == 6) a6 += g;
        else if (cl == 7) a7 += g;
        else if (cl == 8) a8 += g;
        else              a9 += g;
    }
    float* cw = comb[chunk][lane];
    cw[0] = s; cw[1] = gmax; cw[2] = (float)amax;
    cw[3] = a0; cw[4] = a1; cw[5] = a2; cw[6] = a3; cw[7] = a4;
    cw[8] = a5; cw[9] = a6; cw[10] = a7; cw[11] = a8; cw[12] = a9;
    __syncthreads();

    if (tid < 64) {
        int row = tid;
        float sum = 0.f, gm = -1.f;
        int am = 0;
        float acc[K_N];
#pragma unroll
        for (int k = 0; k < K_N; ++k) acc[k] = 0.f;
#pragma unroll
        for (int ch = 0; ch < 4; ++ch) {
            const float* cr = comb[ch][row];
            sum += cr[0];
            if (cr[1] > gm) { gm = cr[1]; am = (int)cr[2]; }
#pragma unroll
            for (int k = 0; k < K_N; ++k) acc[k] += cr[3 + k];
        }
        float den = sum + EPS_F;
        float inv = 1.0f / den;
        float best = -1.f;
        int bk = 0;
        float ls[K_N];
#pragma unroll
        for (int k = 0; k < K_N; ++k) {
            ls[k] = acc[k] * inv;
            if (ls[k] > best) { best = ls[k]; bk = k; }
        }
        int bb = b0 + row;
#pragma unroll
        for (int k = 0; k < K_N; ++k) out[(size_t)bb * K_N + k] = ls[k];
        out[(size_t)B_N * K_N + bb] = (float)bk;
        out[(size_t)B_N * K_N + B_N + bb] = (float)am;
    }
}

// ---------------------------------------------------------------------------
extern "C" void kernel_launch(void* const* d_in, const int* in_sizes, int n_in,
                              void* d_out, int out_size, void* d_ws, size_t ws_size,
                              hipStream_t stream) {
    const float* data   = (const float*)d_in[0];   // [B, D]
    const float* mu     = (const float*)d_in[1];   // [C, D]
    const float* S      = (const float*)d_in[2];   // [C, D, D]
    const int*   onehot = (const int*)d_in[3];     // [C, K]
    float* out = (float*)d_out;

    // ws: Gamma [C][B] | P [C*PPAD] | Sm [C*D] | t3 [C] | cls [C]
    float* gws = (float*)d_ws;
    float* P   = gws + (size_t)C_N * B_N;
    float* Sm  = P + (size_t)C_N * PPAD;
    float* t3  = Sm + C_N * D_N;
    int*   cls = (int*)(t3 + C_N);

    hipLaunchKernelGGL(k_prep_sm, dim3((C_N * D_N) / 256), dim3(256), 0, stream,
                       S, mu, Sm);
    hipLaunchKernelGGL(k_prep_misc, dim3(1), dim3(128), 0, stream,
                       mu, Sm, onehot, t3, cls);
    hipLaunchKernelGGL(k_pack, dim3(C_N), dim3(256), 0, stream,
                       S, Sm, t3, P);
    hipLaunchKernelGGL(k_main, dim3(B_N / 256, C_N / CTILE), dim3(256), 0, stream,
                       data, P, gws);
    hipLaunchKernelGGL(k_final, dim3(B_N / 64), dim3(256), 0, stream,
                       gws, cls, out);
}